// Round 6
// baseline (168.287 us; speedup 1.0000x reference)
//
#include <hip/hip_runtime.h>
#include <math.h>

#define HXc 3.0f
#define HZc 0.25f
#define JZc (-1.0f)

// ws layout (float offsets)
#define OFF_TANR 0         // [256*256] tan(theta) row-major [m][l]
#define OFF_TANT 65536     // [256*256] transposed [l][m]
#define OFF_CPR  131072    // [256] per-row product of cos(theta)
#define OFF_DNT  131328    // [512*256] per-halfblock partial dN_dtheta/2
#define OFF_DDT  262400    // [512*256]
#define OFF_NM   393472    // [512]
#define OFF_DM   393984    // [512]
#define OFF_CN   394496    // [512]
#define OFF_CD   395008    // [512]
#define OFF_CNT  395520    // [1] completion counter (uint), zeroed by k_prep

__device__ __forceinline__ float tan_poly(float x) {
    float y = x * x;
    float p = fmaf(y, 62.0f / 2835.0f, 17.0f / 315.0f);
    p = fmaf(y, p, 2.0f / 15.0f);
    p = fmaf(y, p, 1.0f / 3.0f);
    return x * fmaf(y, p, 1.0f);
}

__device__ __forceinline__ float cos_poly(float x) {
    float y = x * x;
    float p = fmaf(y, 1.0f / 40320.0f, -1.0f / 720.0f);
    p = fmaf(y, p, 1.0f / 24.0f);
    p = fmaf(y, p, -0.5f);
    return fmaf(y, p, 1.0f);
}

// block = m, thread = l: tan tables (row + transposed) + per-row cos product.
__global__ __launch_bounds__(256) void k_prep(const float* __restrict__ theta,
                                              float* __restrict__ ws) {
    int m = blockIdx.x, t = threadIdx.x;
    float x = theta[m * 256 + t];
    float tn = tan_poly(x);
    float c = cos_poly(x);
    ws[OFF_TANR + m * 256 + t] = tn;
    ws[OFF_TANT + t * 256 + m] = tn;
    float pr = c;
    for (int o = 32; o; o >>= 1) pr *= __shfl_xor(pr, o);
    __shared__ float pp[4];
    if ((t & 63) == 0) pp[t >> 6] = pr;
    __syncthreads();
    if (t == 0) ws[OFF_CPR + m] = pp[0] * pp[1] * pp[2] * pp[3];
    if (m == 0 && t == 0) ((unsigned*)(ws + OFF_CNT))[0] = 0u;   // re-init each call
}

// 512 blocks (g = m*2 + half, half owns 128 b's) x 512 threads (8 waves).
// Phase A: forward; Phase B: gradient; last-arriving block runs the finale.
__global__ __launch_bounds__(512) void k_main(
        const float* __restrict__ coef,
        const float* __restrict__ strengths,
        float* __restrict__ ws,
        float* __restrict__ out) {
    int g = blockIdx.x;
    int m = g >> 1;
    int boff = (g & 1) * 128;
    int tid = threadIdx.x;
    const float* __restrict__ tanR = ws + OFF_TANR;
    const float* __restrict__ tanT = ws + OFF_TANT;
    const float* __restrict__ Cpr = ws + OFF_CPR;

    __shared__ float sLDS[256];          // strengths, padded (s[255]=0)
    __shared__ float tmL[256];           // tan row m
    __shared__ float4 quart[4][128];     // phase-A partials (pw,u,v,z)
    __shared__ float Flds[128], cPlds[128];
    __shared__ float wr[2][4];
    __shared__ float gN[8 * 256];
    __shared__ float gD[8 * 256];

    if (tid < 256) {
        sLDS[tid] = (tid < 255) ? strengths[tid] : 0.0f;
        tmL[tid] = tanR[m * 256 + tid];
    }
    __syncthreads();

    // ---- Phase A ----
    {
        int bl = tid & 127, q = tid >> 7;
        int b = boff + bl;
        int l0 = q * 64;
        float pw = 1.0f, u = 0.0f, v = 0.0f, z = 0.0f, a_prev = 0.0f;
        if (q) {
            int l = l0 - 1;
            float qq = tmL[l] * tanT[l * 256 + b];
            a_prev = (1.0f - qq) * __builtin_amdgcn_rcpf(1.0f + qq);
        }
        for (int l = l0; l < l0 + 64; ++l) {
            float tm = tmL[l];                     // LDS broadcast
            float tb = tanT[l * 256 + b];          // coalesced global (L2)
            float qq = tm * tb;
            float w1 = 1.0f + qq;
            float inv = __builtin_amdgcn_rcpf(w1);
            pw *= w1;
            u = fmaf(tm + tb, inv, u);             // sins/cosd
            float a = fmaf(-qq, inv, inv);         // coss/cosd
            v += a;
            float sPrev = (l > 0) ? sLDS[l - 1] : 0.0f;
            z = fmaf(sPrev * a_prev, a, z);
            a_prev = a;
        }
        quart[q][bl] = make_float4(pw, u, v, z);
    }
    __syncthreads();

    // ---- Combine quarters: F/cP to LDS, per-halfblock reductions ----
    if (tid < 128) {
        int b = boff + tid;
        float4 A = quart[0][tid], B = quart[1][tid];
        float4 C = quart[2][tid], Dq = quart[3][tid];
        float P = Cpr[m] * Cpr[b] * (A.x * B.x * C.x * Dq.x);
        float U = A.y + B.y + C.y + Dq.y;
        float V = A.z + B.z + C.z + Dq.z;
        float Z = A.w + B.w + C.w + Dq.w;
        float F = HZc * V + HXc * U + JZc * Z;
        float cP = coef[b] * P;
        Flds[tid] = F;
        cPlds[tid] = cP;
        float base = coef[m] * cP;
        float s1 = base, s2 = base * F, s3 = cP, s4 = cP * F;
        for (int o = 32; o; o >>= 1) {
            s1 += __shfl_xor(s1, o);
            s2 += __shfl_xor(s2, o);
            s3 += __shfl_xor(s3, o);
            s4 += __shfl_xor(s4, o);
        }
        if ((tid & 63) == 0) {
            int w = tid >> 6;
            wr[w][0] = s1; wr[w][1] = s2; wr[w][2] = s3; wr[w][3] = s4;
        }
    }
    __syncthreads();
    if (tid == 0) {
        ws[OFF_DM + g] = wr[0][0] + wr[1][0];
        ws[OFF_NM + g] = wr[0][1] + wr[1][1];
        ws[OFF_CD + g] = wr[0][2] + wr[1][2];
        ws[OFF_CN + g] = wr[0][3] + wr[1][3];
    }

    // ---- Phase B: gradient. wave = 16-b chunk, lane = 4 consecutive l's ----
    {
        int w = tid >> 6, lane = tid & 63;
        int l0 = lane * 4;
        float coefm = coef[m];
        float4 tm4 = *(const float4*)&tmL[l0];
        float tm[4] = {tm4.x, tm4.y, tm4.z, tm4.w};
        float tm2[4] = {2.0f * tm4.x, 2.0f * tm4.y, 2.0f * tm4.z, 2.0f * tm4.w};
        float sR[4], sL[4];
#pragma unroll
        for (int j = 0; j < 4; ++j) {
            int l = l0 + j;
            sR[j] = sLDS[l];
            sL[j] = (l > 0) ? sLDS[l - 1] : 0.0f;
        }
        float pN[4] = {0.f, 0.f, 0.f, 0.f};
        float pD[4] = {0.f, 0.f, 0.f, 0.f};

        for (int i = 0; i < 16; ++i) {
            int bl = w * 16 + i;
            int b = boff + bl;
            float4 tb4 = *(const float4*)&tanR[b * 256 + l0];
            float tb[4] = {tb4.x, tb4.y, tb4.z, tb4.w};
            float Fv = Flds[bl];
            float base = coefm * cPlds[bl];

            float A[4], S[4], G[4];
#pragma unroll
            for (int j = 0; j < 4; ++j) {
                float qq = tm[j] * tb[j];
                float w1 = 1.0f + qq;
                float inv = __builtin_amdgcn_rcpf(w1);
                G[j] = (tm[j] - tb[j]) * inv;
                S[j] = fmaf(tm2[j], inv, -G[j]);   // (tm+tb)*inv
                A[j] = fmaf(-qq, inv, inv);        // (1-qq)*inv
            }
            float aLn = __shfl_up(A[3], 1);
            if (lane == 0) aLn = 0.0f;
            float aRn = __shfl_down(A[0], 1);
            if (lane == 63) aRn = 0.0f;
            float am1[4] = {aLn, A[0], A[1], A[2]};
            float ap1[4] = {A[1], A[2], A[3], aRn};
#pragma unroll
            for (int j = 0; j < 4; ++j) {
                float Gxz = fmaf(HXc, A[j], -HZc * S[j])
                          + fmaf(HZc, A[j], HXc * S[j]) * G[j];
                float K = fmaf(-A[j], G[j], S[j]);          // JZ=-1 folded
                float inc = fmaf(sR[j], ap1[j], sL[j] * am1[j]);
                float term = fmaf(K, inc, Gxz);
                term = fmaf(-Fv, G[j], term);
                pN[j] = fmaf(base, term, pN[j]);
                pD[j] = fmaf(-base, G[j], pD[j]);
            }
        }
        ((float4*)gN)[w * 64 + lane] = make_float4(pN[0], pN[1], pN[2], pN[3]);
        ((float4*)gD)[w * 64 + lane] = make_float4(pD[0], pD[1], pD[2], pD[3]);
    }
    __syncthreads();
    if (tid < 256) {
        float sn = 0.0f, sd = 0.0f;
#pragma unroll
        for (int ww = 0; ww < 8; ++ww) {
            sn += gN[ww * 256 + tid];
            sd += gD[ww * 256 + tid];
        }
        ws[OFF_DNT + g * 256 + tid] = sn;
        ws[OFF_DDT + g * 256 + tid] = sd;
    }

    // ---- last-block finale (replaces k_fin) ----
    __threadfence();
    __shared__ unsigned lastFlag;
    if (tid == 0) {
        unsigned prev = atomicAdd((unsigned*)(ws + OFF_CNT), 1u);
        lastFlag = (prev == 511u) ? 1u : 0u;
    }
    __syncthreads();
    if (!lastFlag) return;
    __threadfence();   // acquire: make all blocks' ws writes visible

    float nv = ws[OFF_NM + tid], dv = ws[OFF_DM + tid];
    for (int o = 32; o; o >>= 1) {
        nv += __shfl_xor(nv, o);
        dv += __shfl_xor(dv, o);
    }
    __shared__ float rn[8], rd[8];
    if ((tid & 63) == 0) { rn[tid >> 6] = nv; rd[tid >> 6] = dv; }
    __syncthreads();
    __shared__ float scal2[2];
    if (tid == 0) {
        float N = 0.0f, D = 0.0f;
#pragma unroll
        for (int k = 0; k < 8; ++k) { N += rn[k]; D += rd[k]; }
        scal2[0] = N / D;
        scal2[1] = 1.0f / D;
    }
    __syncthreads();
    float E = scal2[0], invD = scal2[1];
    float s2 = 2.0f * invD;

    const float4* dnt4 = (const float4*)(ws + OFF_DNT);
    const float4* ddt4 = (const float4*)(ws + OFF_DDT);
    float4* out4 = (float4*)out;
    for (int i = tid; i < 16384; i += 512) {       // i = m*64 + l4
        int mI = i >> 6, l4 = i & 63;
        float4 a0 = dnt4[(mI * 2) * 64 + l4];
        float4 a1 = dnt4[(mI * 2 + 1) * 64 + l4];
        float4 b0 = ddt4[(mI * 2) * 64 + l4];
        float4 b1 = ddt4[(mI * 2 + 1) * 64 + l4];
        float4 r;
        r.x = s2 * ((a0.x + a1.x) - E * (b0.x + b1.x));
        r.y = s2 * ((a0.y + a1.y) - E * (b0.y + b1.y));
        r.z = s2 * ((a0.z + a1.z) - E * (b0.z + b1.z));
        r.w = s2 * ((a0.w + a1.w) - E * (b0.w + b1.w));
        out4[i] = r;
    }
    if (tid < 256) {
        float cn = ws[OFF_CN + 2 * tid] + ws[OFF_CN + 2 * tid + 1];
        float cd = ws[OFF_CD + 2 * tid] + ws[OFF_CD + 2 * tid + 1];
        out[65536 + tid] = s2 * (cn - E * cd);
    }
    if (tid == 0) out[65792] = E * (1.0f / 256.0f);
}

extern "C" void kernel_launch(void* const* d_in, const int* in_sizes, int n_in,
                              void* d_out, int out_size, void* d_ws, size_t ws_size,
                              hipStream_t stream) {
    const float* theta = (const float*)d_in[0];
    const float* coef = (const float*)d_in[1];
    const float* strengths = (const float*)d_in[4];
    float* out = (float*)d_out;
    float* ws = (float*)d_ws;

    k_prep<<<256, 256, 0, stream>>>(theta, ws);
    k_main<<<512, 512, 0, stream>>>(coef, strengths, ws, out);
}

// Round 7
// 94.116 us; speedup vs baseline: 1.7881x; 1.7881x over previous
//
#include <hip/hip_runtime.h>
#include <math.h>

#define HXc 3.0f
#define HZc 0.25f

// ws layout (float offsets)
#define OFF_DNT  0        // [512*256] per-halfblock partial dN_dtheta/2
#define OFF_DDT  131072   // [512*256]
#define OFF_NM   262144   // [512]
#define OFF_DM   262656   // [512]
#define OFF_CN   263168   // [512]
#define OFF_CD   263680   // [512]

__device__ __forceinline__ float tan_poly(float x) {
    // |x| <= 0.3: err < 2e-8 relative
    float y = x * x;
    float p = fmaf(y, 62.0f / 2835.0f, 17.0f / 315.0f);
    p = fmaf(y, p, 2.0f / 15.0f);
    p = fmaf(y, p, 1.0f / 3.0f);
    return x * fmaf(y, p, 1.0f);
}

__device__ __forceinline__ float cos_poly(float x) {
    float y = x * x;
    float p = fmaf(y, 1.0f / 40320.0f, -1.0f / 720.0f);
    p = fmaf(y, p, 1.0f / 24.0f);
    p = fmaf(y, p, -0.5f);
    return fmaf(y, p, 1.0f);
}

// 512 blocks (g = m*2 + half; half owns 128 b's) x 512 threads (8 waves).
// Stage 0: tan/cos of row m from theta. Phase A: forward (tan recomputed
// per-element from theta; cos product folded into pw). Phase B: gradient
// (tan recomputed from coalesced float4 theta row reads).
__global__ __launch_bounds__(512) void k_main(
        const float* __restrict__ theta,
        const float* __restrict__ coef,
        const float* __restrict__ strengths,
        float* __restrict__ ws) {
    int g = blockIdx.x;
    int m = g >> 1;
    int boff = (g & 1) * 128;
    int tid = threadIdx.x;

    __shared__ float sLDS[256];          // strengths, padded (s[255]=0)
    __shared__ float tmL[256];           // tan of row m
    __shared__ float prp[4];             // cos-product partials for row m
    __shared__ float4 quart[4][128];     // phase-A partials (pw,u,v,z)
    __shared__ float Flds[128], cPlds[128];
    __shared__ float wr[2][4];
    __shared__ float gN[8 * 256];
    __shared__ float gD[8 * 256];

    if (tid < 256) {
        float x = theta[m * 256 + tid];      // coalesced
        sLDS[tid] = (tid < 255) ? strengths[tid] : 0.0f;
        tmL[tid] = tan_poly(x);
        float pr = cos_poly(x);
        for (int o = 32; o; o >>= 1) pr *= __shfl_xor(pr, o);
        if ((tid & 63) == 0) prp[tid >> 6] = pr;
    }
    __syncthreads();
    float Cpm = prp[0] * prp[1] * prp[2] * prp[3];  // Π cos(theta[m][l])

    // ---- Phase A: thread -> (l-quarter q, local column bl) ----
    {
        int bl = tid & 127, q = tid >> 7;
        int b = boff + bl;
        const float* __restrict__ thb = theta + b * 256;
        int l0 = q * 64;
        float pw = 1.0f, u = 0.0f, v = 0.0f, z = 0.0f, a_prev = 0.0f;
        if (q) {
            float tb = tan_poly(thb[l0 - 1]);
            float qq = tmL[l0 - 1] * tb;
            a_prev = (1.0f - qq) * __builtin_amdgcn_rcpf(1.0f + qq);
        }
        for (int l4 = l0; l4 < l0 + 64; l4 += 4) {
            float4 th4 = *(const float4*)&thb[l4];  // per-thread serial; L1-line reuse
            float th[4] = {th4.x, th4.y, th4.z, th4.w};
#pragma unroll
            for (int j = 0; j < 4; ++j) {
                int l = l4 + j;
                float tb = tan_poly(th[j]);
                float cb = cos_poly(th[j]);
                float tm = tmL[l];                  // LDS broadcast
                float qq = tm * tb;
                float w1 = 1.0f + qq;
                float inv = __builtin_amdgcn_rcpf(w1);
                pw *= cb * w1;                      // folds Cp[b] into product
                u = fmaf(tm + tb, inv, u);          // sins/cosd
                float a = fmaf(-qq, inv, inv);      // coss/cosd
                v += a;
                float sPrev = (l > 0) ? sLDS[l - 1] : 0.0f;
                z = fmaf(sPrev * a_prev, a, z);
                a_prev = a;
            }
        }
        quart[q][bl] = make_float4(pw, u, v, z);
    }
    __syncthreads();

    // ---- Combine quarters: F/cP to LDS, per-halfblock reductions ----
    if (tid < 128) {
        int b = boff + tid;
        float4 A = quart[0][tid], B = quart[1][tid];
        float4 C = quart[2][tid], Dq = quart[3][tid];
        float P = Cpm * (A.x * B.x * C.x * Dq.x);   // = Cp[m]*Cp[b]*Π(1+q)
        float U = A.y + B.y + C.y + Dq.y;
        float V = A.z + B.z + C.z + Dq.z;
        float Z = A.w + B.w + C.w + Dq.w;
        float F = HZc * V + HXc * U - Z;            // JZ=-1 folded
        float cP = coef[b] * P;
        Flds[tid] = F;
        cPlds[tid] = cP;
        float base = coef[m] * cP;
        float s1 = base, s2 = base * F, s3 = cP, s4 = cP * F;
        for (int o = 32; o; o >>= 1) {
            s1 += __shfl_xor(s1, o);
            s2 += __shfl_xor(s2, o);
            s3 += __shfl_xor(s3, o);
            s4 += __shfl_xor(s4, o);
        }
        if ((tid & 63) == 0) {
            int w = tid >> 6;
            wr[w][0] = s1; wr[w][1] = s2; wr[w][2] = s3; wr[w][3] = s4;
        }
    }
    __syncthreads();
    if (tid == 0) {
        ws[OFF_DM + g] = wr[0][0] + wr[1][0];
        ws[OFF_NM + g] = wr[0][1] + wr[1][1];
        ws[OFF_CD + g] = wr[0][2] + wr[1][2];
        ws[OFF_CN + g] = wr[0][3] + wr[1][3];
    }

    // ---- Phase B: gradient. wave = 16-b chunk, lane = 4 consecutive l's ----
    {
        int w = tid >> 6, lane = tid & 63;
        int l0 = lane * 4;
        float coefm = coef[m];
        float4 tm4 = *(const float4*)&tmL[l0];
        float tm[4] = {tm4.x, tm4.y, tm4.z, tm4.w};
        float tm2[4] = {2.0f * tm4.x, 2.0f * tm4.y, 2.0f * tm4.z, 2.0f * tm4.w};
        float sR[4], sL[4];
#pragma unroll
        for (int j = 0; j < 4; ++j) {
            int l = l0 + j;
            sR[j] = sLDS[l];
            sL[j] = (l > 0) ? sLDS[l - 1] : 0.0f;
        }
        float pN[4] = {0.f, 0.f, 0.f, 0.f};
        float pD[4] = {0.f, 0.f, 0.f, 0.f};

        for (int i = 0; i < 16; ++i) {
            int bl = w * 16 + i;
            int b = boff + bl;
            float4 th4 = *(const float4*)&theta[b * 256 + l0];  // coalesced
            float tb[4] = {tan_poly(th4.x), tan_poly(th4.y),
                           tan_poly(th4.z), tan_poly(th4.w)};
            float Fv = Flds[bl];
            float base = coefm * cPlds[bl];

            float A[4], S[4], G[4];
#pragma unroll
            for (int j = 0; j < 4; ++j) {
                float qq = tm[j] * tb[j];
                float w1 = 1.0f + qq;
                float inv = __builtin_amdgcn_rcpf(w1);
                G[j] = (tm[j] - tb[j]) * inv;
                S[j] = fmaf(tm2[j], inv, -G[j]);   // (tm+tb)*inv
                A[j] = fmaf(-qq, inv, inv);        // (1-qq)*inv
            }
            float aLn = __shfl_up(A[3], 1);
            if (lane == 0) aLn = 0.0f;
            float aRn = __shfl_down(A[0], 1);
            if (lane == 63) aRn = 0.0f;
            float am1[4] = {aLn, A[0], A[1], A[2]};
            float ap1[4] = {A[1], A[2], A[3], aRn};
#pragma unroll
            for (int j = 0; j < 4; ++j) {
                float Gxz = fmaf(HXc, A[j], -HZc * S[j])
                          + fmaf(HZc, A[j], HXc * S[j]) * G[j];
                float K = fmaf(-A[j], G[j], S[j]);          // JZ=-1 folded
                float inc = fmaf(sR[j], ap1[j], sL[j] * am1[j]);
                float term = fmaf(K, inc, Gxz);
                term = fmaf(-Fv, G[j], term);
                pN[j] = fmaf(base, term, pN[j]);
                pD[j] = fmaf(-base, G[j], pD[j]);
            }
        }
        ((float4*)gN)[w * 64 + lane] = make_float4(pN[0], pN[1], pN[2], pN[3]);
        ((float4*)gD)[w * 64 + lane] = make_float4(pD[0], pD[1], pD[2], pD[3]);
    }
    __syncthreads();
    if (tid < 256) {
        float sn = 0.0f, sd = 0.0f;
#pragma unroll
        for (int ww = 0; ww < 8; ++ww) {
            sn += gN[ww * 256 + tid];
            sd += gD[ww * 256 + tid];
        }
        ws[OFF_DNT + g * 256 + tid] = sn;
        ws[OFF_DDT + g * 256 + tid] = sd;
    }
}

// 256 blocks x 256 thr: redundant deterministic N/D reduction, then scale.
__global__ __launch_bounds__(256) void k_fin(const float* __restrict__ ws,
                                             float* __restrict__ out) {
    int m = blockIdx.x, t = threadIdx.x;
    float nv = ws[OFF_NM + t] + ws[OFF_NM + 256 + t];
    float dv = ws[OFF_DM + t] + ws[OFF_DM + 256 + t];
    for (int o = 32; o; o >>= 1) {
        nv += __shfl_xor(nv, o);
        dv += __shfl_xor(dv, o);
    }
    __shared__ float rn[4], rd[4];
    if ((t & 63) == 0) { rn[t >> 6] = nv; rd[t >> 6] = dv; }
    __syncthreads();
    float N = rn[0] + rn[1] + rn[2] + rn[3];
    float D = rd[0] + rd[1] + rd[2] + rd[3];
    float E = N / D;
    float invD = 1.0f / D;
    int g0 = m * 2, g1 = m * 2 + 1;
    float sn = ws[OFF_DNT + g0 * 256 + t] + ws[OFF_DNT + g1 * 256 + t];
    float sd = ws[OFF_DDT + g0 * 256 + t] + ws[OFF_DDT + g1 * 256 + t];
    out[m * 256 + t] = 2.0f * invD * (sn - E * sd);
    if (t == 0) {
        float cn = ws[OFF_CN + g0] + ws[OFF_CN + g1];
        float cd = ws[OFF_CD + g0] + ws[OFF_CD + g1];
        out[65536 + m] = 2.0f * invD * (cn - E * cd);
    }
    if (m == 0 && t == 1) out[65792] = E * (1.0f / 256.0f);
}

extern "C" void kernel_launch(void* const* d_in, const int* in_sizes, int n_in,
                              void* d_out, int out_size, void* d_ws, size_t ws_size,
                              hipStream_t stream) {
    const float* theta = (const float*)d_in[0];
    const float* coef = (const float*)d_in[1];
    const float* strengths = (const float*)d_in[4];
    float* out = (float*)d_out;
    float* ws = (float*)d_ws;

    k_main<<<512, 512, 0, stream>>>(theta, coef, strengths, ws);
    k_fin<<<256, 256, 0, stream>>>(ws, out);
}

// Round 8
// 91.422 us; speedup vs baseline: 1.8408x; 1.0295x over previous
//
#include <hip/hip_runtime.h>
#include <math.h>

#define HXc 3.0f
#define HZc 0.25f

// ws layout (float offsets)
#define OFF_TANR 0        // [256*256] tan(theta) row-major [m][l]
#define OFF_F    65536    // [256*256] F[m][b]
#define OFF_CP   131072   // [256*256] cP[m][b] = coef[b]*P[m][b]
#define OFF_NM   196608   // [256] per-m sum_b base*F
#define OFF_DM   196864   // [256] per-m sum_b base
#define OFF_CN   197120   // [256] per-m sum_b cP*F
#define OFF_CD   197376   // [256] per-m sum_b cP

__device__ __forceinline__ float tan_poly(float x) {
    // |x| <= 0.3: rel err < 2e-8
    float y = x * x;
    float p = fmaf(y, 62.0f / 2835.0f, 17.0f / 315.0f);
    p = fmaf(y, p, 2.0f / 15.0f);
    p = fmaf(y, p, 1.0f / 3.0f);
    return x * fmaf(y, p, 1.0f);
}

__device__ __forceinline__ float cos_poly(float x) {
    float y = x * x;
    float p = fmaf(y, 1.0f / 40320.0f, -1.0f / 720.0f);
    p = fmaf(y, p, 1.0f / 24.0f);
    p = fmaf(y, p, -0.5f);
    return fmaf(y, p, 1.0f);
}

// 256 blocks (block = m) x 512 threads. Phase A: subwave (16 lanes) per b,
// each lane owns 16 consecutive l's; coalesced theta row reads; butterfly
// reduces. Writes tanR row m, F/cP rows, per-m N/D/cN/cD partials.
__global__ __launch_bounds__(512) void k_fwd(
        const float* __restrict__ theta,
        const float* __restrict__ coef,
        const float* __restrict__ strengths,
        float* __restrict__ ws) {
    int m = blockIdx.x, tid = threadIdx.x;
    __shared__ float tmL[256], sLDS[256], Flds[256], cPlds[256];
    __shared__ float prp[4];
    __shared__ float red[32][4];

    if (tid < 256) {
        float x = theta[m * 256 + tid];                 // coalesced
        float tn = tan_poly(x);
        tmL[tid] = tn;
        ws[OFF_TANR + m * 256 + tid] = tn;              // own row only
        sLDS[tid] = (tid < 255) ? strengths[tid] : 0.0f;
        float pr = cos_poly(x);
        for (int o = 32; o; o >>= 1) pr *= __shfl_xor(pr, o);
        if ((tid & 63) == 0) prp[tid >> 6] = pr;
    }
    __syncthreads();
    float Cpm = prp[0] * prp[1] * prp[2] * prp[3];      // prod cos(theta[m][:])
    float coefm = coef[m];

    int w = tid >> 6, lane = tid & 63;
    int sw = lane >> 4, sl = lane & 15;
    int l0 = sl * 16;

    // one-time per-lane preloads (l-range fixed across all b)
    float tm[16], sLv[16];
#pragma unroll
    for (int j = 0; j < 16; ++j) {
        tm[j] = tmL[l0 + j];
        int lm1 = l0 + j - 1;
        sLv[j] = (lm1 >= 0) ? sLDS[lm1] : 0.0f;         // s[l-1]
    }

    float nA = 0.f, dA = 0.f, cNA = 0.f, cDA = 0.f;
    for (int r = 0; r < 8; ++r) {
        int b = r * 32 + w * 4 + sw;                    // 32 b's per round
        const float4* thp = (const float4*)&theta[b * 256 + l0];
        float4 t0 = thp[0], t1 = thp[1], t2 = thp[2], t3 = thp[3];
        float th[16] = {t0.x, t0.y, t0.z, t0.w, t1.x, t1.y, t1.z, t1.w,
                        t2.x, t2.y, t2.z, t2.w, t3.x, t3.y, t3.z, t3.w};
        float pl = 1.f, ul = 0.f, vl = 0.f, zl = 0.f;
        float a_prev = 0.f, a_first = 0.f;
#pragma unroll
        for (int j = 0; j < 16; ++j) {
            float tb = tan_poly(th[j]);
            float cb = cos_poly(th[j]);
            float qq = tm[j] * tb;
            float w1 = 1.0f + qq;
            float inv = __builtin_amdgcn_rcpf(w1);
            pl *= cb * w1;                              // folds cos(theta[b][l])
            ul = fmaf(tm[j] + tb, inv, ul);             // sins/cosd
            float a = fmaf(-qq, inv, inv);              // coss/cosd
            vl += a;
            if (j == 0) a_first = a;
            else        zl = fmaf(sLv[j] * a_prev, a, zl);
            a_prev = a;
        }
        // boundary pair (l0-1, l0) via prev lane's last a
        float aP = __shfl_up(a_prev, 1);
        float sB = (sl == 0) ? 0.0f : sLv[0];
        zl = fmaf(sB * aP, a_first, zl);
        // butterfly within 16-lane subwave
#pragma unroll
        for (int o = 1; o < 16; o <<= 1) {
            pl *= __shfl_xor(pl, o);
            ul += __shfl_xor(ul, o);
            vl += __shfl_xor(vl, o);
            zl += __shfl_xor(zl, o);
        }
        float P = Cpm * pl;                             // Cp[m]*Cp[b]*prod(1+q)
        float F = fmaf(HZc, vl, fmaf(HXc, ul, -zl));    // JZ=-1 folded
        float cP = coef[b] * P;
        if (sl == 0) { Flds[b] = F; cPlds[b] = cP; }
        float base = coefm * cP;
        dA += base;
        nA = fmaf(base, F, nA);
        cDA += cP;
        cNA = fmaf(cP, F, cNA);
    }
    if (sl == 0) {
        int s = w * 4 + sw;
        red[s][0] = nA; red[s][1] = dA; red[s][2] = cNA; red[s][3] = cDA;
    }
    __syncthreads();
    if (tid < 256) {
        ws[OFF_F + m * 256 + tid] = Flds[tid];
        ws[OFF_CP + m * 256 + tid] = cPlds[tid];
    }
    if (tid < 32) {
        float v0 = red[tid][0], v1 = red[tid][1];
        float v2 = red[tid][2], v3 = red[tid][3];
#pragma unroll
        for (int o = 1; o < 32; o <<= 1) {
            v0 += __shfl_xor(v0, o);
            v1 += __shfl_xor(v1, o);
            v2 += __shfl_xor(v2, o);
            v3 += __shfl_xor(v3, o);
        }
        if (tid == 0) {
            ws[OFF_NM + m] = v0; ws[OFF_DM + m] = v1;
            ws[OFF_CN + m] = v2; ws[OFF_CD + m] = v3;
        }
    }
}

// 256 blocks (block = m) x 512 threads (8 waves). Redundant deterministic
// N/D reduction, then R5's phase B (32 b-iters/wave), final outputs direct.
__global__ __launch_bounds__(512) void k_grad(
        const float* __restrict__ coef,
        const float* __restrict__ strengths,
        const float* __restrict__ ws,
        float* __restrict__ out) {
    int m = blockIdx.x, tid = threadIdx.x;
    const float* __restrict__ tanR = ws + OFF_TANR;
    __shared__ float sLDS[256], Flds[256], cPlds[256];
    __shared__ float gN[8 * 256], gD[8 * 256];
    __shared__ float rn[4], rd[4];

    if (tid < 256) {
        sLDS[tid] = (tid < 255) ? strengths[tid] : 0.0f;
        Flds[tid] = ws[OFF_F + m * 256 + tid];
        cPlds[tid] = ws[OFF_CP + m * 256 + tid];
        float nv = ws[OFF_NM + tid], dv = ws[OFF_DM + tid];
        for (int o = 32; o; o >>= 1) {
            nv += __shfl_xor(nv, o);
            dv += __shfl_xor(dv, o);
        }
        if ((tid & 63) == 0) { rn[tid >> 6] = nv; rd[tid >> 6] = dv; }
    }
    __syncthreads();
    float N = rn[0] + rn[1] + rn[2] + rn[3];
    float D = rd[0] + rd[1] + rd[2] + rd[3];
    float E = N / D;                  // bit-identical in every block
    float invD = 1.0f / D;
    float s2 = 2.0f * invD;

    // ---- Phase B: wave = 32-b chunk, lane = 4 consecutive l's ----
    {
        int w = tid >> 6, lane = tid & 63;
        int l0 = lane * 4;
        float coefm = coef[m];
        float4 tm4 = *(const float4*)&tanR[m * 256 + l0];
        float tm[4] = {tm4.x, tm4.y, tm4.z, tm4.w};
        float tm2[4] = {2.0f * tm4.x, 2.0f * tm4.y, 2.0f * tm4.z, 2.0f * tm4.w};
        float sR[4], sL[4];
#pragma unroll
        for (int j = 0; j < 4; ++j) {
            int l = l0 + j;
            sR[j] = sLDS[l];
            sL[j] = (l > 0) ? sLDS[l - 1] : 0.0f;
        }
        float pN[4] = {0.f, 0.f, 0.f, 0.f};
        float pD[4] = {0.f, 0.f, 0.f, 0.f};

        for (int i = 0; i < 32; ++i) {
            int b = w * 32 + i;
            float4 tb4 = *(const float4*)&tanR[b * 256 + l0];   // coalesced, L2-hot
            float tb[4] = {tb4.x, tb4.y, tb4.z, tb4.w};
            float Fv = Flds[b];
            float base = coefm * cPlds[b];

            float A[4], S[4], G[4];
#pragma unroll
            for (int j = 0; j < 4; ++j) {
                float qq = tm[j] * tb[j];
                float w1 = 1.0f + qq;
                float inv = __builtin_amdgcn_rcpf(w1);
                G[j] = (tm[j] - tb[j]) * inv;
                S[j] = fmaf(tm2[j], inv, -G[j]);   // (tm+tb)*inv
                A[j] = fmaf(-qq, inv, inv);        // (1-qq)*inv
            }
            float aLn = __shfl_up(A[3], 1);
            if (lane == 0) aLn = 0.0f;
            float aRn = __shfl_down(A[0], 1);
            if (lane == 63) aRn = 0.0f;
            float am1[4] = {aLn, A[0], A[1], A[2]};
            float ap1[4] = {A[1], A[2], A[3], aRn};
#pragma unroll
            for (int j = 0; j < 4; ++j) {
                float Gxz = fmaf(HXc, A[j], -HZc * S[j])
                          + fmaf(HZc, A[j], HXc * S[j]) * G[j];
                float K = fmaf(-A[j], G[j], S[j]);          // JZ=-1 folded
                float inc = fmaf(sR[j], ap1[j], sL[j] * am1[j]);
                float term = fmaf(K, inc, Gxz);
                term = fmaf(-Fv, G[j], term);
                pN[j] = fmaf(base, term, pN[j]);
                pD[j] = fmaf(-base, G[j], pD[j]);
            }
        }
        ((float4*)gN)[w * 64 + lane] = make_float4(pN[0], pN[1], pN[2], pN[3]);
        ((float4*)gD)[w * 64 + lane] = make_float4(pD[0], pD[1], pD[2], pD[3]);
    }
    __syncthreads();
    if (tid < 256) {
        float sn = 0.0f, sd = 0.0f;
#pragma unroll
        for (int ww = 0; ww < 8; ++ww) {
            sn += gN[ww * 256 + tid];
            sd += gD[ww * 256 + tid];
        }
        out[m * 256 + tid] = s2 * (sn - E * sd);
    }
    if (tid == 0)
        out[65536 + m] = s2 * (ws[OFF_CN + m] - E * ws[OFF_CD + m]);
    if (m == 0 && tid == 1)
        out[65792] = E * (1.0f / 256.0f);
}

extern "C" void kernel_launch(void* const* d_in, const int* in_sizes, int n_in,
                              void* d_out, int out_size, void* d_ws, size_t ws_size,
                              hipStream_t stream) {
    const float* theta = (const float*)d_in[0];
    const float* coef = (const float*)d_in[1];
    const float* strengths = (const float*)d_in[4];
    float* out = (float*)d_out;
    float* ws = (float*)d_ws;

    k_fwd<<<256, 512, 0, stream>>>(theta, coef, strengths, ws);
    k_grad<<<256, 512, 0, stream>>>(coef, strengths, ws, out);
}